// Round 10
// baseline (100.638 us; speedup 1.0000x reference)
//
#include <hip/hip_runtime.h>

typedef unsigned short u16;
typedef __attribute__((ext_vector_type(4))) float f32x4;
typedef __attribute__((ext_vector_type(4))) int i32x4;
typedef __attribute__((ext_vector_type(8))) __bf16 bf16x8;
typedef __attribute__((ext_vector_type(4))) unsigned short u16x4;

#define BATCH 16384
#define NINP 256
#define HID 1024
#define NOUT 16

// ---------- helpers ----------
__device__ __forceinline__ u16 f2bf(float f) {
  unsigned u = __builtin_bit_cast(unsigned, f);
  u += 0x7FFFu + ((u >> 16) & 1u);   // round-to-nearest-even
  return (u16)(u >> 16);
}
__device__ __forceinline__ f32x4 mfma_bb(bf16x8 a, bf16x8 b, f32x4 c) {
  return __builtin_amdgcn_mfma_f32_16x16x32_bf16(a, b, c, 0, 0, 0);
}
__device__ __forceinline__ void gload_lds16(const void* g, void* l) {
  __builtin_amdgcn_global_load_lds(
      (const __attribute__((address_space(1))) void*)g,
      (__attribute__((address_space(3))) void*)l, 16, 0, 0);
}

// ---------- workspace layout (bytes) ----------
// H1 is ELIMINATED (W2-fold fused into gemm2). part_uni aliases H0 (dead
// after gemm2 reads it; k_uni runs after gemm2). part_fold lives in the old
// H1/xb region (xb dead after gemm1; gemm2 writes fold partials there).
static const size_t OFF_H0    = 0;          // 33,554,432  H0 bf16 [16384][1024]
static const size_t OFF_PARTU = 0;          //  8,388,608  part_uni f32 [8][16384][16]
static const size_t OFF_XB    = 33554432;   //  8,388,608  x bf16
static const size_t OFF_PARTF = 33554432;   //  4,194,304  part_fold f32 [4][16384][16]
static const size_t OFF_W0T   = 67108864;   //    524,288  W0^T bf16 [1024][256]
static const size_t OFF_W1T   = 67633152;   //  2,097,152  W1^T bf16 [1024][1024]
static const size_t OFF_W2T   = 69730304;   //     32,768  W2^T bf16 [16][1024]
static const size_t OFF_UWP   = 69763072;   //  1,048,576  packed uni blobs, 4096B/feature
static const size_t OFF_CB    = 70811648;   //        256  cb f32 [16]

// ---------- merged prep: transposes + converts + packing ----------
__global__ __launch_bounds__(256) void k_prep(
    const float* __restrict__ x,
    const float* __restrict__ W0, const float* __restrict__ W1,
    const float* __restrict__ W2,
    const float* __restrict__ uw1, const float* __restrict__ ub1,
    const float* __restrict__ uw2, const float* __restrict__ ub2,
    const float* __restrict__ uw3, const float* __restrict__ b2,
    const float* __restrict__ ub3,
    u16* __restrict__ xb,
    u16* __restrict__ W0T, u16* __restrict__ W1T, u16* __restrict__ W2T,
    char* __restrict__ uwp, float* __restrict__ cb)
{
  __shared__ float tile[32][33];
  const int bid = blockIdx.x;
  const int tid = threadIdx.x;

  if (bid < 1312) {                       // weight transposes f32[K][N] -> bf16[N][K]
    const float* src; u16* dst; int K, N, kb, ob;
    if (bid < 256)       { src = W0; dst = W0T; K = 256;  N = 1024; int t = bid;        kb = (t & 7) * 32;  ob = (t >> 3) * 32; }
    else if (bid < 1280) { src = W1; dst = W1T; K = 1024; N = 1024; int t = bid - 256;  kb = (t & 31) * 32; ob = (t >> 5) * 32; }
    else                 { src = W2; dst = W2T; K = 1024; N = 16;   int t = bid - 1280; kb = t * 32;        ob = 0; }
    const int tx = tid & 31, ty = tid >> 5;
    for (int r = ty; r < 32; r += 8)
      if (ob + tx < N) tile[r][tx] = src[(size_t)(kb + r) * N + ob + tx];
    __syncthreads();
    for (int r = ty; r < 32; r += 8)
      if (ob + r < N) dst[(size_t)(ob + r) * K + kb + tx] = f2bf(tile[tx][r]);
  } else if (bid < 5408) {                // x -> bf16
    const int idx = ((bid - 1312) * 256 + tid) * 4;
    const float4 v = *(const float4*)&x[idx];
    u16x4 o4 = { f2bf(v.x), f2bf(v.y), f2bf(v.z), f2bf(v.w) };
    *(u16x4*)&xb[idx] = o4;
  } else if (bid < 5664) {                // uw2 -> puw2 fragments
    const int e = ((bid - 5408) * 256 + tid) * 4;
    const float4 v = *(const float4*)&uw2[e];
    const int i = e >> 10, f = (e >> 5) & 31, o = e & 31;
    const float vv[4] = { v.x, v.y, v.z, v.w };
    u16* blob16 = (u16*)(uwp + (size_t)i * 4096);
#pragma unroll
    for (int d = 0; d < 4; ++d) {
      const int oo = o + d;
      const int lane = ((f >> 3) << 4) | (oo & 15);
      blob16[256 + (oo >> 4) * 512 + lane * 8 + (f & 7)] = f2bf(vv[d]);
    }
  } else if (bid < 5792) {                // uw3 -> puw3 fragments (k-slot perm)
    const int e = ((bid - 5664) * 256 + tid) * 4;
    const float4 v = *(const float4*)&uw3[e];
    const int i = e >> 9, f = (e >> 4) & 31, o2 = e & 15;
    const int s = (f < 16) ? (((f >> 2) << 3) + (f & 3))
                           : ((((f - 16) >> 2) << 3) + 4 + (f & 3));
    const float vv[4] = { v.x, v.y, v.z, v.w };
    u16* blob16 = (u16*)(uwp + (size_t)i * 4096);
#pragma unroll
    for (int d = 0; d < 4; ++d)
      blob16[1280 + ((s >> 3) * 16 + o2 + d) * 8 + (s & 7)] = f2bf(vv[d]);
  } else if (bid < 5816) {                // uw1/ub1/ub2 f32 copy into blobs
    const int e4 = (bid - 5792) * 256 + tid;      // float4 index, 0..6143
    const int i = e4 / 24, r4 = e4 % 24;
    const float* src = (r4 < 8)  ? &uw1[i * 32 + r4 * 4]
                     : (r4 < 16) ? &ub1[i * 32 + (r4 - 8) * 4]
                                 : &ub2[i * 32 + (r4 - 16) * 4];
    *(float4*)(uwp + (size_t)i * 4096 + r4 * 16) = *(const float4*)src;
  } else {                                // cb[o] = b2[o] + sum_i ub3[i][o]
    __shared__ float red[16][16];
    const int ig = tid >> 4, o = tid & 15;
    float s = 0.f;
#pragma unroll
    for (int k = 0; k < 16; ++k) s += ub3[(ig * 16 + k) * 16 + o];
    red[ig][o] = s;
    __syncthreads();
    if (tid < 16) {
      float t = b2[tid];
#pragma unroll
      for (int k = 0; k < 16; ++k) t += red[k][tid];
      cb[tid] = t;
    }
  }
}

// ---------- 8-wave 256x256 MFMA GEMM, BK=64, swizzled LDS, counted vmcnt ----
// template<KT, FOLD>: KT = compile-time K (distinct rocprof symbol per GEMM).
// FOLD=false: C = relu(A @ BT^T + bias), bf16 store via LDS-bounce.
// FOLD=true : output is NOT stored; instead relu'd tile is folded against
//   W2T (256-K chunk, 16 outputs) via MFMA and written as f32 partials
//   part_fold[bn][rows][16] -- H1 never materializes.
template<int KT, bool FOLD>
__global__ __launch_bounds__(512, 2) void k_gemm8(
    const u16* __restrict__ A, const u16* __restrict__ BT,
    const float* __restrict__ bias, u16* __restrict__ C,
    const u16* __restrict__ W2Tp, float* __restrict__ pfold, int N)
{
  extern __shared__ __align__(16) char lds[];
  const int tid = threadIdx.x;
  const int lane = tid & 63, wid = tid >> 6;
  const int l15 = lane & 15, g = lane >> 4;
  const int wA = wid >> 2;
  const int wn = wid & 3;
  const int nbn = N >> 8;
  int logical = blockIdx.x;
  { const int nwg = gridDim.x;
    if ((nwg & 7) == 0) { const int q = nwg >> 3; logical = (logical & 7) * q + (logical >> 3); } }
  const int bm = logical / nbn, bn = logical - bm * nbn;
  const size_t rb = (size_t)bm * 256, cb = (size_t)bn * 256;

  const int q7 = l15 & 7;
  const int arow0 = wA * 128 + l15;
  const int brow0 = wn * 64 + l15;

  char* const ldsA = lds;            // 2 x 32 KiB
  char* const ldsB = lds + 65536;    // 2 x 32 KiB

  const u16* Ag = A + rb * KT;
  const u16* Bg = BT + cb * KT;

  // W2 fragments + bias pre-load (before staging: oldest in vmcnt order,
  // long landed before any counted wait matters)
  bf16x8 w2f[8];
  if constexpr (FOLD) {
#pragma unroll
    for (int c = 0; c < 8; ++c)
      w2f[c] = __builtin_bit_cast(bf16x8,
          *(const i32x4*)&W2Tp[l15 * HID + (int)cb + c * 32 + g * 8]);
  }
  float bv[4];
#pragma unroll
  for (int n = 0; n < 4; ++n) bv[n] = bias[cb + wn * 64 + n * 16 + l15];

  f32x4 acc[8][4] = {};
  const int NT = KT >> 6;

#define STAGE(arr, src, ktE, s) do { \
    const int G_ = (s) * 512 + tid; \
    const int row_ = G_ >> 3; \
    const int c8_ = (G_ & 7) ^ (row_ & 7); \
    gload_lds16(&(src)[(size_t)row_ * KT + (ktE) + c8_ * 8], (arr) + G_ * 16); \
  } while (0)

#define ARD(bp, m, kk) (*(const bf16x8*)((bp) + (((arow0 + (m) * 16) * 8 + (((kk) * 4 + g) ^ q7)) << 4)))
#define BRD(bp, n, kk) (*(const bf16x8*)((bp) + (((brow0 + (n) * 16) * 8 + (((kk) * 4 + g) ^ q7)) << 4)))

  // prologue: stage tile 0 into buf 0 in canonical order, counted wait, publish
  STAGE(ldsB, Bg, 0, 0); STAGE(ldsB, Bg, 0, 1);
  STAGE(ldsB, Bg, 0, 2); STAGE(ldsB, Bg, 0, 3);
  STAGE(ldsA, Ag, 0, 0); STAGE(ldsA, Ag, 0, 2);
  STAGE(ldsA, Ag, 0, 1); STAGE(ldsA, Ag, 0, 3);
  asm volatile("s_waitcnt vmcnt(2)" ::: "memory");
  __builtin_amdgcn_s_barrier();

  for (int t = 0; t < NT; ++t) {
    const int b = t & 1;
    const char* Ab = ldsA + b * 32768;
    const char* Bb = ldsB + b * 32768;
    char* An = ldsA + (b ^ 1) * 32768;
    char* Bn = ldsB + (b ^ 1) * 32768;
    const int tn = (t + 1 < NT) ? t + 1 : 0;   // wrap keeps counts uniform
    const int kt1 = tn << 6;
    bf16x8 av[4][2], bv0[2][2], bv1[2][2];

    // ---- phase 0: read A m0-3, B n0-1; stage B0,B1(t+1); MFMA m0-3 x n0-1
#pragma unroll
    for (int m = 0; m < 4; ++m) { av[m][0] = ARD(Ab, m, 0); av[m][1] = ARD(Ab, m, 1); }
#pragma unroll
    for (int n = 0; n < 2; ++n) { bv0[n][0] = BRD(Bb, n, 0); bv0[n][1] = BRD(Bb, n, 1); }
    STAGE(Bn, Bg, kt1, 0); STAGE(Bn, Bg, kt1, 1);
    __builtin_amdgcn_s_barrier();
    __builtin_amdgcn_s_setprio(1);
#pragma unroll
    for (int m = 0; m < 4; ++m)
#pragma unroll
      for (int n = 0; n < 2; ++n) {
        acc[m][n] = mfma_bb(av[m][0], bv0[n][0], acc[m][n]);
        acc[m][n] = mfma_bb(av[m][1], bv0[n][1], acc[m][n]);
      }
    __builtin_amdgcn_s_setprio(0);
    __builtin_amdgcn_s_barrier();

    // ---- phase 1: read B n2-3; stage B2,B3; MFMA m0-3 x n2-3; vmcnt(4)
#pragma unroll
    for (int n = 0; n < 2; ++n) { bv1[n][0] = BRD(Bb, n + 2, 0); bv1[n][1] = BRD(Bb, n + 2, 1); }
    STAGE(Bn, Bg, kt1, 2); STAGE(Bn, Bg, kt1, 3);
    __builtin_amdgcn_s_barrier();
    __builtin_amdgcn_s_setprio(1);
#pragma unroll
    for (int m = 0; m < 4; ++m)
#pragma unroll
      for (int n = 0; n < 2; ++n) {
        acc[m][n + 2] = mfma_bb(av[m][0], bv1[n][0], acc[m][n + 2]);
        acc[m][n + 2] = mfma_bb(av[m][1], bv1[n][1], acc[m][n + 2]);
      }
    __builtin_amdgcn_s_setprio(0);
    asm volatile("s_waitcnt vmcnt(4)" ::: "memory");
    __builtin_amdgcn_s_barrier();

    // ---- phase 2: read A m4-7; stage A0,A2; MFMA m4-7 x n2-3
#pragma unroll
    for (int m = 0; m < 4; ++m) { av[m][0] = ARD(Ab, m + 4, 0); av[m][1] = ARD(Ab, m + 4, 1); }
    STAGE(An, Ag, kt1, 0); STAGE(An, Ag, kt1, 2);
    __builtin_amdgcn_s_barrier();
    __builtin_amdgcn_s_setprio(1);
#pragma unroll
    for (int m = 0; m < 4; ++m)
#pragma unroll
      for (int n = 0; n < 2; ++n) {
        acc[m + 4][n + 2] = mfma_bb(av[m][0], bv1[n][0], acc[m + 4][n + 2]);
        acc[m + 4][n + 2] = mfma_bb(av[m][1], bv1[n][1], acc[m + 4][n + 2]);
      }
    __builtin_amdgcn_s_setprio(0);
    __builtin_amdgcn_s_barrier();

    // ---- phase 3: stage A1,A3; MFMA m4-7 x n0-1; tile-end vmcnt(2)
    STAGE(An, Ag, kt1, 1); STAGE(An, Ag, kt1, 3);
    __builtin_amdgcn_s_setprio(1);
#pragma unroll
    for (int m = 0; m < 4; ++m)
#pragma unroll
      for (int n = 0; n < 2; ++n) {
        acc[m + 4][n] = mfma_bb(av[m][0], bv0[n][0], acc[m + 4][n]);
        acc[m + 4][n] = mfma_bb(av[m][1], bv0[n][1], acc[m + 4][n]);
      }
    __builtin_amdgcn_s_setprio(0);
    asm volatile("s_waitcnt vmcnt(2)" ::: "memory");
    __builtin_amdgcn_s_barrier();
  }
#undef STAGE
#undef ARD
#undef BRD

  // drain wrap-stages before reusing the staging LDS for the epilogue bounce
  asm volatile("s_waitcnt vmcnt(0)" ::: "memory");

  // ---- epilogue: bias+relu into LDS bounce; then either coalesced bf16
  //      stores (FOLD=false) or the W2 MFMA fold (FOLD=true)
  {
    char* const ep = lds;              // [128 lrow][256 col] bf16, XOR-swizzled
#pragma unroll
    for (int h = 0; h < 2; ++h) {
      __syncthreads();                 // region free (drained / prev round read)
#pragma unroll
      for (int mloc = 0; mloc < 4; ++mloc)
#pragma unroll
        for (int n = 0; n < 4; ++n) {
          const int col = wn * 64 + n * 16 + l15;
#pragma unroll
          for (int r = 0; r < 4; ++r) {
            const int lrow = wA * 64 + mloc * 16 + g * 4 + r;
            *(u16*)(ep + lrow * 512 + ((col * 2) ^ ((lrow & 7) << 4))) =
                f2bf(fmaxf(acc[h * 4 + mloc][n][r] + bv[n], 0.f));
          }
        }
      __syncthreads();
      if constexpr (!FOLD) {
        // read back 16B/lane (conflict-free) -> 512B-contiguous global stores
#pragma unroll
        for (int p = 0; p < 8; ++p) {
          const int ci = p * 512 + tid;
          const int lrow = ci >> 5, c16 = ci & 31;
          const i32x4 v = *(const i32x4*)(ep + lrow * 512 + ((c16 * 16) ^ ((lrow & 7) << 4)));
          const int grow = (int)rb + (lrow >> 6) * 128 + h * 64 + (lrow & 63);
          *(i32x4*)&C[(size_t)grow * N + cb + c16 * 8] = v;
        }
      } else {
        // fold: wave wid owns LDS rows wid*16..+15; A-frag lane (g,l15):
        // A[row=l15][k=g*8+j] from LDS; B = w2f (W2T[o2=l15][k=g*8+j]).
        // D[row=4g+r][o2=l15] -> part_fold[bn][grow][o2].
        const int lrow = wid * 16 + l15;
        f32x4 accf = {0.f, 0.f, 0.f, 0.f};
#pragma unroll
        for (int c = 0; c < 8; ++c) {
          const bf16x8 afr = *(const bf16x8*)(
              ep + lrow * 512 + ((c * 64 + g * 16) ^ ((lrow & 7) << 4)));
          accf = mfma_bb(afr, w2f[c], accf);
        }
        const int rowb2 = (int)rb + (wid >> 2) * 128 + h * 64 + (wid & 3) * 16;
        float* pf = pfold + ((size_t)bn * BATCH + rowb2) * NOUT;
#pragma unroll
        for (int r = 0; r < 4; ++r)
          pf[(g * 4 + r) * NOUT + l15] = accf[r];
      }
    }
  }
}

// ---------- uni MLPs only (W2 tail moved into gemm2 fold), 8 chunks ----------
__global__ __launch_bounds__(256, 4) void k_uni(
    const float* __restrict__ x,
    const char* __restrict__ uwp,
    float* __restrict__ part)
{
  const int tid = threadIdx.x, lane = tid & 63, wid = tid >> 6;
  const int l15 = lane & 15, g = lane >> 4;
  const int chunk = blockIdx.x & 7, rowblk = blockIdx.x >> 3;
  const int rb_blk = rowblk * 128;
  const int rb = rb_blk + wid * 32;
  const int i0 = chunk * 32;

  __shared__ __align__(16) float xt[128][33];   // odd stride: conflict-free
  __shared__ __align__(16) char wbuf[2][4096];  // double-buffered weight blobs

  {
    const int r0 = tid >> 3, c4 = (tid & 7) << 2;
#pragma unroll
    for (int rr = 0; rr < 128; rr += 32)
      *(float4*)&xt[rr + r0][c4] =
          *(const float4*)&x[(size_t)(rb_blk + rr + r0) * NINP + i0 + c4];
  }
  gload_lds16(uwp + (size_t)i0 * 4096 + tid * 16, &wbuf[0][tid * 16]);
  __syncthreads();

  const f32x4 zero4 = {0.f, 0.f, 0.f, 0.f};
  f32x4 acc0 = zero4, acc1 = zero4;
  const float* xr0 = &xt[wid * 32 + l15][0];
  const float* xr1 = &xt[wid * 32 + 16 + l15][0];

#pragma unroll 2
  for (int ii = 0; ii < 32; ++ii) {
    const int nxt = (ii + 1) & 31;
    gload_lds16(uwp + (size_t)(i0 + nxt) * 4096 + tid * 16,
                &wbuf[(ii + 1) & 1][tid * 16]);

    const char* bp = &wbuf[ii & 1][0];
    const f32x4 w1lo = *(const f32x4*)(bp + g * 32);
    const f32x4 w1hi = *(const f32x4*)(bp + g * 32 + 16);
    const f32x4 b1lo = *(const f32x4*)(bp + 128 + g * 32);
    const f32x4 b1hi = *(const f32x4*)(bp + 128 + g * 32 + 16);
    const f32x4 bb0  = *(const f32x4*)(bp + 256 + g * 16);
    const f32x4 bb1  = *(const f32x4*)(bp + 320 + g * 16);
    const bf16x8 bv0 = *(const bf16x8*)(bp + 512 + lane * 16);
    const bf16x8 bv1 = *(const bf16x8*)(bp + 1536 + lane * 16);
    const bf16x8 b3  = *(const bf16x8*)(bp + 2560 + lane * 16);
    const float xv0 = xr0[ii], xv1 = xr1[ii];

    bf16x8 af0, af1;
#pragma unroll
    for (int j = 0; j < 4; ++j) {
      af0[j]     = (__bf16)fmaxf(fmaf(xv0, w1lo[j], b1lo[j]), 0.f);
      af0[4 + j] = (__bf16)fmaxf(fmaf(xv0, w1hi[j], b1hi[j]), 0.f);
      af1[j]     = (__bf16)fmaxf(fmaf(xv1, w1lo[j], b1lo[j]), 0.f);
      af1[4 + j] = (__bf16)fmaxf(fmaf(xv1, w1hi[j], b1hi[j]), 0.f);
    }

    const f32x4 d00 = mfma_bb(bv0, af0, bb0);
    const f32x4 d10 = mfma_bb(bv1, af0, bb1);
    const f32x4 d01 = mfma_bb(bv0, af1, bb0);
    const f32x4 d11 = mfma_bb(bv1, af1, bb1);

    bf16x8 h20, h21;
#pragma unroll
    for (int j = 0; j < 4; ++j) {
      h20[j]     = (__bf16)fmaxf(d00[j], 0.f);
      h20[4 + j] = (__bf16)fmaxf(d10[j], 0.f);
      h21[j]     = (__bf16)fmaxf(d01[j], 0.f);
      h21[4 + j] = (__bf16)fmaxf(d11[j], 0.f);
    }

    acc0 = mfma_bb(b3, h20, acc0);
    acc1 = mfma_bb(b3, h21, acc1);

    __syncthreads();
  }

  float* p = part + ((size_t)chunk * BATCH + rb) * NOUT;
  *(f32x4*)&p[l15 * 16 + g * 4] = acc0;
  *(f32x4*)&p[(16 + l15) * 16 + g * 4] = acc1;
}

// ---------- reduce 8 uni partials + 4 fold partials + cb -> out ----------
__global__ __launch_bounds__(256) void k_reduce(
    const float* __restrict__ pu, const float* __restrict__ pf,
    const float* __restrict__ cb, float* __restrict__ out)
{
  const int j4 = blockIdx.x * 256 + threadIdx.x;   // 65536 float4's
  const float4 c = ((const float4*)cb)[j4 & 3];
  const float4* a4 = (const float4*)pu;
  const float4* b4 = (const float4*)pf;
  float rx = c.x, ry = c.y, rz = c.z, rw = c.w;
#pragma unroll
  for (int cc = 0; cc < 8; ++cc) {
    const float4 a = a4[cc * 65536 + j4];
    rx += a.x; ry += a.y; rz += a.z; rw += a.w;
  }
#pragma unroll
  for (int cc = 0; cc < 4; ++cc) {
    const float4 a = b4[cc * 65536 + j4];
    rx += a.x; ry += a.y; rz += a.z; rw += a.w;
  }
  float4 r; r.x = rx; r.y = ry; r.z = rz; r.w = rw;
  ((float4*)out)[j4] = r;
}

extern "C" void kernel_launch(void* const* d_in, const int* in_sizes, int n_in,
                              void* d_out, int out_size, void* d_ws, size_t ws_size,
                              hipStream_t stream) {
  (void)in_sizes; (void)n_in; (void)out_size; (void)ws_size;
  const float* x   = (const float*)d_in[0];
  const float* W0  = (const float*)d_in[1];
  const float* b0  = (const float*)d_in[2];
  const float* W1  = (const float*)d_in[3];
  const float* b1  = (const float*)d_in[4];
  const float* W2  = (const float*)d_in[5];
  const float* b2  = (const float*)d_in[6];
  const float* uw1 = (const float*)d_in[7];
  const float* ub1 = (const float*)d_in[8];
  const float* uw2 = (const float*)d_in[9];
  const float* ub2 = (const float*)d_in[10];
  const float* uw3 = (const float*)d_in[11];
  const float* ub3 = (const float*)d_in[12];
  float* out = (float*)d_out;

  char* ws = (char*)d_ws;
  u16*   H0    = (u16*)(ws + OFF_H0);
  u16*   xb    = (u16*)(ws + OFF_XB);
  u16*   W0T   = (u16*)(ws + OFF_W0T);
  u16*   W1T   = (u16*)(ws + OFF_W1T);
  u16*   W2T   = (u16*)(ws + OFF_W2T);
  char*  uwp   = (char*)(ws + OFF_UWP);
  float* cb    = (float*)(ws + OFF_CB);
  float* partu = (float*)(ws + OFF_PARTU);
  float* partf = (float*)(ws + OFF_PARTF);

  // allow 128 KiB dynamic LDS for the GEMMs (idempotent; capture-safe)
  hipFuncSetAttribute((const void*)k_gemm8<256, false>,
                      hipFuncAttributeMaxDynamicSharedMemorySize, 131072);
  hipFuncSetAttribute((const void*)k_gemm8<1024, true>,
                      hipFuncAttributeMaxDynamicSharedMemorySize, 131072);

  k_prep<<<5817, 256, 0, stream>>>(x, W0, W1, W2, uw1, ub1, uw2, ub2, uw3,
                                   b2, ub3, xb, W0T, W1T, W2T, uwp, cb);
  k_gemm8<256, false><<<256, 512, 131072, stream>>>(
      xb, W0T, b0, H0, nullptr, nullptr, HID);
  k_gemm8<1024, true><<<256, 512, 131072, stream>>>(
      H0, W1T, b1, nullptr, W2T, partf, HID);
  k_uni<<<1024, 256, 0, stream>>>(x, uwp, partu);
  k_reduce<<<256, 256, 0, stream>>>(partu, partf, cb, out);
}

// Round 11
// 95.892 us; speedup vs baseline: 1.0495x; 1.0495x over previous
//
#include <hip/hip_runtime.h>

typedef unsigned short u16;
typedef __attribute__((ext_vector_type(4))) float f32x4;
typedef __attribute__((ext_vector_type(4))) int i32x4;
typedef __attribute__((ext_vector_type(8))) __bf16 bf16x8;
typedef __attribute__((ext_vector_type(4))) unsigned short u16x4;

#define BATCH 16384
#define NINP 256
#define HID 1024
#define NOUT 16

// ---------- helpers ----------
__device__ __forceinline__ u16 f2bf(float f) {
  unsigned u = __builtin_bit_cast(unsigned, f);
  u += 0x7FFFu + ((u >> 16) & 1u);   // round-to-nearest-even
  return (u16)(u >> 16);
}
__device__ __forceinline__ f32x4 mfma_bb(bf16x8 a, bf16x8 b, f32x4 c) {
  return __builtin_amdgcn_mfma_f32_16x16x32_bf16(a, b, c, 0, 0, 0);
}
__device__ __forceinline__ void gload_lds16(const void* g, void* l) {
  __builtin_amdgcn_global_load_lds(
      (const __attribute__((address_space(1))) void*)g,
      (__attribute__((address_space(3))) void*)l, 16, 0, 0);
}

// ---------- workspace layout (bytes) ----------
static const size_t OFF_H0    = 0;          // 33,554,432  H0 bf16 [16384][1024]
static const size_t OFF_PARTU = 0;          //  8,388,608  part_uni f32 [8][16384][16] (aliases dead H0)
static const size_t OFF_XB    = 33554432;   //  8,388,608  x bf16
static const size_t OFF_PARTF = 33554432;   //  4,194,304  part_fold f32 [4][16384][16] (aliases dead xb)
static const size_t OFF_W0T   = 67108864;   //    524,288  W0^T bf16 [1024][256]
static const size_t OFF_W1T   = 67633152;   //  2,097,152  W1^T bf16 [1024][1024]
static const size_t OFF_W2T   = 69730304;   //     32,768  W2^T bf16 [16][1024]
static const size_t OFF_UWP   = 69763072;   //  1,048,576  packed uni blobs, 4096B/feature
static const size_t OFF_CB    = 70811648;   //        256  cb f32 [16]

// ---------- merged prep: transposes + converts + packing ----------
__global__ __launch_bounds__(256) void k_prep(
    const float* __restrict__ x,
    const float* __restrict__ W0, const float* __restrict__ W1,
    const float* __restrict__ W2,
    const float* __restrict__ uw1, const float* __restrict__ ub1,
    const float* __restrict__ uw2, const float* __restrict__ ub2,
    const float* __restrict__ uw3, const float* __restrict__ b2,
    const float* __restrict__ ub3,
    u16* __restrict__ xb,
    u16* __restrict__ W0T, u16* __restrict__ W1T, u16* __restrict__ W2T,
    char* __restrict__ uwp, float* __restrict__ cb)
{
  __shared__ float tile[32][33];
  const int bid = blockIdx.x;
  const int tid = threadIdx.x;

  if (bid < 1312) {                       // weight transposes f32[K][N] -> bf16[N][K]
    const float* src; u16* dst; int K, N, kb, ob;
    if (bid < 256)       { src = W0; dst = W0T; K = 256;  N = 1024; int t = bid;        kb = (t & 7) * 32;  ob = (t >> 3) * 32; }
    else if (bid < 1280) { src = W1; dst = W1T; K = 1024; N = 1024; int t = bid - 256;  kb = (t & 31) * 32; ob = (t >> 5) * 32; }
    else                 { src = W2; dst = W2T; K = 1024; N = 16;   int t = bid - 1280; kb = t * 32;        ob = 0; }
    const int tx = tid & 31, ty = tid >> 5;
    for (int r = ty; r < 32; r += 8)
      if (ob + tx < N) tile[r][tx] = src[(size_t)(kb + r) * N + ob + tx];
    __syncthreads();
    for (int r = ty; r < 32; r += 8)
      if (ob + r < N) dst[(size_t)(ob + r) * K + kb + tx] = f2bf(tile[tx][r]);
  } else if (bid < 5408) {                // x -> bf16
    const int idx = ((bid - 1312) * 256 + tid) * 4;
    const float4 v = *(const float4*)&x[idx];
    u16x4 o4 = { f2bf(v.x), f2bf(v.y), f2bf(v.z), f2bf(v.w) };
    *(u16x4*)&xb[idx] = o4;
  } else if (bid < 5664) {                // uw2 -> puw2 fragments
    const int e = ((bid - 5408) * 256 + tid) * 4;
    const float4 v = *(const float4*)&uw2[e];
    const int i = e >> 10, f = (e >> 5) & 31, o = e & 31;
    const float vv[4] = { v.x, v.y, v.z, v.w };
    u16* blob16 = (u16*)(uwp + (size_t)i * 4096);
#pragma unroll
    for (int d = 0; d < 4; ++d) {
      const int oo = o + d;
      const int lane = ((f >> 3) << 4) | (oo & 15);
      blob16[256 + (oo >> 4) * 512 + lane * 8 + (f & 7)] = f2bf(vv[d]);
    }
  } else if (bid < 5792) {                // uw3 -> puw3 fragments (k-slot perm)
    const int e = ((bid - 5664) * 256 + tid) * 4;
    const float4 v = *(const float4*)&uw3[e];
    const int i = e >> 9, f = (e >> 4) & 31, o2 = e & 15;
    const int s = (f < 16) ? (((f >> 2) << 3) + (f & 3))
                           : ((((f - 16) >> 2) << 3) + 4 + (f & 3));
    const float vv[4] = { v.x, v.y, v.z, v.w };
    u16* blob16 = (u16*)(uwp + (size_t)i * 4096);
#pragma unroll
    for (int d = 0; d < 4; ++d)
      blob16[1280 + ((s >> 3) * 16 + o2 + d) * 8 + (s & 7)] = f2bf(vv[d]);
  } else if (bid < 5816) {                // uw1/ub1/ub2 f32 copy into blobs
    const int e4 = (bid - 5792) * 256 + tid;      // float4 index, 0..6143
    const int i = e4 / 24, r4 = e4 % 24;
    const float* src = (r4 < 8)  ? &uw1[i * 32 + r4 * 4]
                     : (r4 < 16) ? &ub1[i * 32 + (r4 - 8) * 4]
                                 : &ub2[i * 32 + (r4 - 16) * 4];
    *(float4*)(uwp + (size_t)i * 4096 + r4 * 16) = *(const float4*)src;
  } else {                                // cb[o] = b2[o] + sum_i ub3[i][o]
    __shared__ float red[16][16];
    const int ig = tid >> 4, o = tid & 15;
    float s = 0.f;
#pragma unroll
    for (int k = 0; k < 16; ++k) s += ub3[(ig * 16 + k) * 16 + o];
    red[ig][o] = s;
    __syncthreads();
    if (tid < 16) {
      float t = b2[tid];
#pragma unroll
      for (int k = 0; k < 16; ++k) t += red[k][tid];
      cb[tid] = t;
    }
  }
}

// ---------- shared GEMM body: 8-wave 256x256, BK=64, swizzled LDS ----------
// Counted vmcnt (never 0 mid-loop); final tile PEELED (no stages) with a
// vmcnt(0) before its A1/A3 reads -- replaces R9's wrap-stage (-16MB fetch).
// m201-faithful lgkm discipline: lgkmcnt(8) before the 12-read phase-0
// barrier, explicit lgkmcnt(0) after each opening barrier.
template<int KT, bool FOLD>
__device__ __forceinline__ void gemm_body(
    const u16* __restrict__ A, const u16* __restrict__ BT,
    const float* __restrict__ bias, u16* __restrict__ C,
    const u16* __restrict__ W2Tp, float* __restrict__ pfold, int N)
{
  extern __shared__ __align__(16) char lds[];
  const int tid = threadIdx.x;
  const int lane = tid & 63, wid = tid >> 6;
  const int l15 = lane & 15, g = lane >> 4;
  const int wA = wid >> 2;
  const int wn = wid & 3;
  const int nbn = N >> 8;
  int logical = blockIdx.x;
  { const int nwg = gridDim.x;
    if ((nwg & 7) == 0) { const int q = nwg >> 3; logical = (logical & 7) * q + (logical >> 3); } }
  const int bm = logical / nbn, bn = logical - bm * nbn;
  const size_t rb = (size_t)bm * 256, cb = (size_t)bn * 256;

  const int q7 = l15 & 7;
  const int arow0 = wA * 128 + l15;
  const int brow0 = wn * 64 + l15;

  char* const ldsA = lds;            // 2 x 32 KiB
  char* const ldsB = lds + 65536;    // 2 x 32 KiB

  const u16* Ag = A + rb * KT;
  const u16* Bg = BT + cb * KT;

  bf16x8 w2f[8];
  if constexpr (FOLD) {
#pragma unroll
    for (int c = 0; c < 8; ++c)
      w2f[c] = __builtin_bit_cast(bf16x8,
          *(const i32x4*)&W2Tp[l15 * HID + (int)cb + c * 32 + g * 8]);
  }
  float bv[4];
#pragma unroll
  for (int n = 0; n < 4; ++n) bv[n] = bias[cb + wn * 64 + n * 16 + l15];

  f32x4 acc[8][4] = {};
  const int NT = KT >> 6;

#define STAGE(arr, src, ktE, s) do { \
    const int G_ = (s) * 512 + tid; \
    const int row_ = G_ >> 3; \
    const int c8_ = (G_ & 7) ^ (row_ & 7); \
    gload_lds16(&(src)[(size_t)row_ * KT + (ktE) + c8_ * 8], (arr) + G_ * 16); \
  } while (0)

#define ARD(bp, m, kk) (*(const bf16x8*)((bp) + (((arow0 + (m) * 16) * 8 + (((kk) * 4 + g) ^ q7)) << 4)))
#define BRD(bp, n, kk) (*(const bf16x8*)((bp) + (((brow0 + (n) * 16) * 8 + (((kk) * 4 + g) ^ q7)) << 4)))

// one K-tile: 4 phases. LASTT: peeled final tile (no stages; vmcnt(0) mid)
#define KTILE(Ab, Bb, An, Bn, kt1, LASTT) do {                                 \
    bf16x8 av[4][2], bv0[2][2], bv1[2][2];                                     \
    /* phase 0: read A m0-3, B n0-1 (12 reads); stage B0,B1 */                 \
    _Pragma("unroll")                                                          \
    for (int m = 0; m < 4; ++m) { av[m][0] = ARD(Ab, m, 0); av[m][1] = ARD(Ab, m, 1); } \
    _Pragma("unroll")                                                          \
    for (int n = 0; n < 2; ++n) { bv0[n][0] = BRD(Bb, n, 0); bv0[n][1] = BRD(Bb, n, 1); } \
    if (!(LASTT)) { STAGE(Bn, Bg, kt1, 0); STAGE(Bn, Bg, kt1, 1); }            \
    asm volatile("s_waitcnt lgkmcnt(8)" ::: "memory");                         \
    __builtin_amdgcn_s_barrier();                                              \
    asm volatile("s_waitcnt lgkmcnt(0)" ::: "memory");                         \
    __builtin_amdgcn_s_setprio(1);                                             \
    _Pragma("unroll")                                                          \
    for (int m = 0; m < 4; ++m)                                                \
      _Pragma("unroll")                                                        \
      for (int n = 0; n < 2; ++n) {                                            \
        acc[m][n] = mfma_bb(av[m][0], bv0[n][0], acc[m][n]);                   \
        acc[m][n] = mfma_bb(av[m][1], bv0[n][1], acc[m][n]);                   \
      }                                                                        \
    __builtin_amdgcn_s_setprio(0);                                             \
    __builtin_amdgcn_s_barrier();                                              \
    /* phase 1: read B n2-3; stage B2,B3; end: A1/A3 of THIS tile land */      \
    _Pragma("unroll")                                                          \
    for (int n = 0; n < 2; ++n) { bv1[n][0] = BRD(Bb, n + 2, 0); bv1[n][1] = BRD(Bb, n + 2, 1); } \
    if (!(LASTT)) { STAGE(Bn, Bg, kt1, 2); STAGE(Bn, Bg, kt1, 3); }            \
    __builtin_amdgcn_s_barrier();                                              \
    asm volatile("s_waitcnt lgkmcnt(0)" ::: "memory");                         \
    __builtin_amdgcn_s_setprio(1);                                             \
    _Pragma("unroll")                                                          \
    for (int m = 0; m < 4; ++m)                                                \
      _Pragma("unroll")                                                        \
      for (int n = 0; n < 2; ++n) {                                            \
        acc[m][n + 2] = mfma_bb(av[m][0], bv1[n][0], acc[m][n + 2]);           \
        acc[m][n + 2] = mfma_bb(av[m][1], bv1[n][1], acc[m][n + 2]);           \
      }                                                                        \
    __builtin_amdgcn_s_setprio(0);                                             \
    if (LASTT) { asm volatile("s_waitcnt vmcnt(0)" ::: "memory"); }            \
    else       { asm volatile("s_waitcnt vmcnt(4)" ::: "memory"); }            \
    __builtin_amdgcn_s_barrier();                                              \
    /* phase 2: read A m4-7; stage A0,A2 */                                    \
    _Pragma("unroll")                                                          \
    for (int m = 0; m < 4; ++m) { av[m][0] = ARD(Ab, m + 4, 0); av[m][1] = ARD(Ab, m + 4, 1); } \
    if (!(LASTT)) { STAGE(An, Ag, kt1, 0); STAGE(An, Ag, kt1, 2); }            \
    __builtin_amdgcn_s_barrier();                                              \
    asm volatile("s_waitcnt lgkmcnt(0)" ::: "memory");                         \
    __builtin_amdgcn_s_setprio(1);                                             \
    _Pragma("unroll")                                                          \
    for (int m = 0; m < 4; ++m)                                                \
      _Pragma("unroll")                                                        \
      for (int n = 0; n < 2; ++n) {                                            \
        acc[m + 4][n + 2] = mfma_bb(av[m][0], bv1[n][0], acc[m + 4][n + 2]);   \
        acc[m + 4][n + 2] = mfma_bb(av[m][1], bv1[n][1], acc[m + 4][n + 2]);   \
      }                                                                        \
    __builtin_amdgcn_s_setprio(0);                                             \
    __builtin_amdgcn_s_barrier();                                              \
    /* phase 3: stage A1,A3; MFMA m4-7 x n0-1; tile-end counted wait */        \
    if (!(LASTT)) { STAGE(An, Ag, kt1, 1); STAGE(An, Ag, kt1, 3); }            \
    __builtin_amdgcn_s_setprio(1);                                             \
    _Pragma("unroll")                                                          \
    for (int m = 0; m < 4; ++m)                                                \
      _Pragma("unroll")                                                        \
      for (int n = 0; n < 2; ++n) {                                            \
        acc[m + 4][n] = mfma_bb(av[m][0], bv0[n][0], acc[m + 4][n]);           \
        acc[m + 4][n] = mfma_bb(av[m][1], bv0[n][1], acc[m + 4][n]);           \
      }                                                                        \
    __builtin_amdgcn_s_setprio(0);                                             \
    if (!(LASTT)) { asm volatile("s_waitcnt vmcnt(2)" ::: "memory"); }         \
    __builtin_amdgcn_s_barrier();                                              \
  } while (0)

  // prologue: stage tile 0 into buf 0 in canonical order, counted wait
  STAGE(ldsB, Bg, 0, 0); STAGE(ldsB, Bg, 0, 1);
  STAGE(ldsB, Bg, 0, 2); STAGE(ldsB, Bg, 0, 3);
  STAGE(ldsA, Ag, 0, 0); STAGE(ldsA, Ag, 0, 2);
  STAGE(ldsA, Ag, 0, 1); STAGE(ldsA, Ag, 0, 3);
  asm volatile("s_waitcnt vmcnt(2)" ::: "memory");
  __builtin_amdgcn_s_barrier();

  for (int t = 0; t < NT - 1; ++t) {
    const int b = t & 1;
    KTILE(ldsA + b * 32768, ldsB + b * 32768,
          ldsA + (b ^ 1) * 32768, ldsB + (b ^ 1) * 32768,
          (t + 1) << 6, false);
  }
  {   // peeled final tile: no stages, vmcnt(0) before its A1/A3 reads
    const int b = (NT - 1) & 1;
    KTILE(ldsA + b * 32768, ldsB + b * 32768,
          ldsA + (b ^ 1) * 32768, ldsB + (b ^ 1) * 32768, 0, true);
  }
#undef KTILE
#undef STAGE
#undef ARD
#undef BRD

  // ---- epilogue: bias+relu into LDS bounce; then stores or W2-fold
  {
    char* const ep = lds;              // [128 lrow][256 col] bf16, XOR-swizzled
#pragma unroll
    for (int h = 0; h < 2; ++h) {
      __syncthreads();
#pragma unroll
      for (int mloc = 0; mloc < 4; ++mloc)
#pragma unroll
        for (int n = 0; n < 4; ++n) {
          const int col = wn * 64 + n * 16 + l15;
#pragma unroll
          for (int r = 0; r < 4; ++r) {
            const int lrow = wA * 64 + mloc * 16 + g * 4 + r;
            *(u16*)(ep + lrow * 512 + ((col * 2) ^ ((lrow & 7) << 4))) =
                f2bf(fmaxf(acc[h * 4 + mloc][n][r] + bv[n], 0.f));
          }
        }
      __syncthreads();
      if constexpr (!FOLD) {
#pragma unroll
        for (int p = 0; p < 8; ++p) {
          const int ci = p * 512 + tid;
          const int lrow = ci >> 5, c16 = ci & 31;
          const i32x4 v = *(const i32x4*)(ep + lrow * 512 + ((c16 * 16) ^ ((lrow & 7) << 4)));
          const int grow = (int)rb + (lrow >> 6) * 128 + h * 64 + (lrow & 63);
          *(i32x4*)&C[(size_t)grow * N + cb + c16 * 8] = v;
        }
      } else {
        const int lrow = wid * 16 + l15;
        f32x4 accf = {0.f, 0.f, 0.f, 0.f};
#pragma unroll
        for (int c = 0; c < 8; ++c) {
          const bf16x8 afr = *(const bf16x8*)(
              ep + lrow * 512 + ((c * 64 + g * 16) ^ ((lrow & 7) << 4)));
          accf = mfma_bb(afr, w2f[c], accf);
        }
        const int rowb2 = (int)rb + (wid >> 2) * 128 + h * 64 + (wid & 3) * 16;
        float* pf = pfold + ((size_t)bn * BATCH + rowb2) * NOUT;
#pragma unroll
        for (int r = 0; r < 4; ++r)
          pf[(g * 4 + r) * NOUT + l15] = accf[r];
      }
    }
  }
}

// distinct symbols for rocprof attribution
__global__ __launch_bounds__(512, 2) void k_g1(
    const u16* __restrict__ A, const u16* __restrict__ BT,
    const float* __restrict__ bias, u16* __restrict__ C, int N)
{
  gemm_body<256, false>(A, BT, bias, C, nullptr, nullptr, N);
}
__global__ __launch_bounds__(512, 2) void k_g2(
    const u16* __restrict__ A, const u16* __restrict__ BT,
    const float* __restrict__ bias, const u16* __restrict__ W2Tp,
    float* __restrict__ pfold, int N)
{
  gemm_body<1024, true>(A, BT, bias, nullptr, W2Tp, pfold, N);
}

// ---------- uni MLPs (W2 tail lives in k_g2's fold), 8 chunks ----------
__global__ __launch_bounds__(256, 4) void k_uni(
    const float* __restrict__ x,
    const char* __restrict__ uwp,
    float* __restrict__ part)
{
  const int tid = threadIdx.x, lane = tid & 63, wid = tid >> 6;
  const int l15 = lane & 15, g = lane >> 4;
  const int chunk = blockIdx.x & 7, rowblk = blockIdx.x >> 3;
  const int rb_blk = rowblk * 128;
  const int rb = rb_blk + wid * 32;
  const int i0 = chunk * 32;

  __shared__ __align__(16) float xt[128][33];   // odd stride: conflict-free
  __shared__ __align__(16) char wbuf[2][4096];  // double-buffered weight blobs

  {
    const int r0 = tid >> 3, c4 = (tid & 7) << 2;
#pragma unroll
    for (int rr = 0; rr < 128; rr += 32)
      *(float4*)&xt[rr + r0][c4] =
          *(const float4*)&x[(size_t)(rb_blk + rr + r0) * NINP + i0 + c4];
  }
  gload_lds16(uwp + (size_t)i0 * 4096 + tid * 16, &wbuf[0][tid * 16]);
  __syncthreads();

  const f32x4 zero4 = {0.f, 0.f, 0.f, 0.f};
  f32x4 acc0 = zero4, acc1 = zero4;
  const float* xr0 = &xt[wid * 32 + l15][0];
  const float* xr1 = &xt[wid * 32 + 16 + l15][0];

#pragma unroll 2
  for (int ii = 0; ii < 32; ++ii) {
    const int nxt = (ii + 1) & 31;
    gload_lds16(uwp + (size_t)(i0 + nxt) * 4096 + tid * 16,
                &wbuf[(ii + 1) & 1][tid * 16]);

    const char* bp = &wbuf[ii & 1][0];
    const f32x4 w1lo = *(const f32x4*)(bp + g * 32);
    const f32x4 w1hi = *(const f32x4*)(bp + g * 32 + 16);
    const f32x4 b1lo = *(const f32x4*)(bp + 128 + g * 32);
    const f32x4 b1hi = *(const f32x4*)(bp + 128 + g * 32 + 16);
    const f32x4 bb0  = *(const f32x4*)(bp + 256 + g * 16);
    const f32x4 bb1  = *(const f32x4*)(bp + 320 + g * 16);
    const bf16x8 bv0 = *(const bf16x8*)(bp + 512 + lane * 16);
    const bf16x8 bv1 = *(const bf16x8*)(bp + 1536 + lane * 16);
    const bf16x8 b3  = *(const bf16x8*)(bp + 2560 + lane * 16);
    const float xv0 = xr0[ii], xv1 = xr1[ii];

    bf16x8 af0, af1;
#pragma unroll
    for (int j = 0; j < 4; ++j) {
      af0[j]     = (__bf16)fmaxf(fmaf(xv0, w1lo[j], b1lo[j]), 0.f);
      af0[4 + j] = (__bf16)fmaxf(fmaf(xv0, w1hi[j], b1hi[j]), 0.f);
      af1[j]     = (__bf16)fmaxf(fmaf(xv1, w1lo[j], b1lo[j]), 0.f);
      af1[4 + j] = (__bf16)fmaxf(fmaf(xv1, w1hi[j], b1hi[j]), 0.f);
    }

    const f32x4 d00 = mfma_bb(bv0, af0, bb0);
    const f32x4 d10 = mfma_bb(bv1, af0, bb1);
    const f32x4 d01 = mfma_bb(bv0, af1, bb0);
    const f32x4 d11 = mfma_bb(bv1, af1, bb1);

    bf16x8 h20, h21;
#pragma unroll
    for (int j = 0; j < 4; ++j) {
      h20[j]     = (__bf16)fmaxf(d00[j], 0.f);
      h20[4 + j] = (__bf16)fmaxf(d10[j], 0.f);
      h21[j]     = (__bf16)fmaxf(d01[j], 0.f);
      h21[4 + j] = (__bf16)fmaxf(d11[j], 0.f);
    }

    acc0 = mfma_bb(b3, h20, acc0);
    acc1 = mfma_bb(b3, h21, acc1);

    __syncthreads();
  }

  float* p = part + ((size_t)chunk * BATCH + rb) * NOUT;
  *(f32x4*)&p[l15 * 16 + g * 4] = acc0;
  *(f32x4*)&p[(16 + l15) * 16 + g * 4] = acc1;
}

// ---------- reduce 8 uni partials + 4 fold partials + cb -> out ----------
__global__ __launch_bounds__(256) void k_reduce(
    const float* __restrict__ pu, const float* __restrict__ pf,
    const float* __restrict__ cb, float* __restrict__ out)
{
  const int j4 = blockIdx.x * 256 + threadIdx.x;   // 65536 float4's
  const float4 c = ((const float4*)cb)[j4 & 3];
  const float4* a4 = (const float4*)pu;
  const float4* b4 = (const float4*)pf;
  float rx = c.x, ry = c.y, rz = c.z, rw = c.w;
#pragma unroll
  for (int cc = 0; cc < 8; ++cc) {
    const float4 a = a4[cc * 65536 + j4];
    rx += a.x; ry += a.y; rz += a.z; rw += a.w;
  }
#pragma unroll
  for (int cc = 0; cc < 4; ++cc) {
    const float4 a = b4[cc * 65536 + j4];
    rx += a.x; ry += a.y; rz += a.z; rw += a.w;
  }
  float4 r; r.x = rx; r.y = ry; r.z = rz; r.w = rw;
  ((float4*)out)[j4] = r;
}

extern "C" void kernel_launch(void* const* d_in, const int* in_sizes, int n_in,
                              void* d_out, int out_size, void* d_ws, size_t ws_size,
                              hipStream_t stream) {
  (void)in_sizes; (void)n_in; (void)out_size; (void)ws_size;
  const float* x   = (const float*)d_in[0];
  const float* W0  = (const float*)d_in[1];
  const float* b0  = (const float*)d_in[2];
  const float* W1  = (const float*)d_in[3];
  const float* b1  = (const float*)d_in[4];
  const float* W2  = (const float*)d_in[5];
  const float* b2  = (const float*)d_in[6];
  const float* uw1 = (const float*)d_in[7];
  const float* ub1 = (const float*)d_in[8];
  const float* uw2 = (const float*)d_in[9];
  const float* ub2 = (const float*)d_in[10];
  const float* uw3 = (const float*)d_in[11];
  const float* ub3 = (const float*)d_in[12];
  float* out = (float*)d_out;

  char* ws = (char*)d_ws;
  u16*   H0    = (u16*)(ws + OFF_H0);
  u16*   xb    = (u16*)(ws + OFF_XB);
  u16*   W0T   = (u16*)(ws + OFF_W0T);
  u16*   W1T   = (u16*)(ws + OFF_W1T);
  u16*   W2T   = (u16*)(ws + OFF_W2T);
  char*  uwp   = (char*)(ws + OFF_UWP);
  float* cb    = (float*)(ws + OFF_CB);
  float* partu = (float*)(ws + OFF_PARTU);
  float* partf = (float*)(ws + OFF_PARTF);

  hipFuncSetAttribute((const void*)k_g1,
                      hipFuncAttributeMaxDynamicSharedMemorySize, 131072);
  hipFuncSetAttribute((const void*)k_g2,
                      hipFuncAttributeMaxDynamicSharedMemorySize, 131072);

  k_prep<<<5817, 256, 0, stream>>>(x, W0, W1, W2, uw1, ub1, uw2, ub2, uw3,
                                   b2, ub3, xb, W0T, W1T, W2T, uwp, cb);
  k_g1<<<256, 512, 131072, stream>>>(xb, W0T, b0, H0, HID);
  k_g2<<<256, 512, 131072, stream>>>(H0, W1T, b1, W2T, partf, HID);
  k_uni<<<1024, 256, 0, stream>>>(x, uwp, partu);
  k_reduce<<<256, 256, 0, stream>>>(partu, partf, cb, out);
}